// Round 2
// baseline (22.055 us; speedup 1.0000x reference)
//
#include <hip/hip_runtime.h>

// out[n,m] = sum_f (note[n,f]-lab[m,f])*W[f] + b
//          = dot(note[n],W) - dot(lab[m],W) + b   (exact factorization)
// Single fused kernel: each block owns R=8 note rows; it recomputes all
// 512 lab dots itself (lab is 512 KB -> L2/L3 resident broadcast), so no
// cross-block dependency and only ONE dispatch (launch overhead dominated).

#define N_ROWS 2048
#define M_ROWS 512
#define FDIM   256
#define RPB    8            // note rows per block
#define NBLK   (N_ROWS / RPB)   // 256 blocks

__global__ __launch_bounds__(256)
void siamese_fused(const float* __restrict__ note,
                   const float* __restrict__ lab,
                   const float* __restrict__ W,
                   const float* __restrict__ bptr,
                   float* __restrict__ out) {
    __shared__ float s_w[FDIM];      // W staged (1 KB)
    __shared__ float s_c[M_ROWS];    // lab dots (2 KB)
    __shared__ float s_a[RPB];       // note dots for this block's rows

    const int t    = threadIdx.x;            // 0..255
    const int blk  = blockIdx.x;             // 0..255
    const int wave = t >> 6;
    const int lane = t & 63;

    // Stage W into LDS (64 float4 loads)
    if (t < 64) {
        reinterpret_cast<float4*>(s_w)[t] = reinterpret_cast<const float4*>(W)[t];
    }
    __syncthreads();

    // --- Note dots for this block's RPB rows: wave-parallel shuffle reduce.
    // Issue these first: note rows are per-block unique (HBM traffic).
    #pragma unroll
    for (int rr = wave; rr < RPB; rr += 4) {
        const int n = blk * RPB + rr;
        float4 v = reinterpret_cast<const float4*>(note + (size_t)n * FDIM)[lane];
        float4 w = reinterpret_cast<const float4*>(s_w)[lane];
        float s = v.x * w.x + v.y * w.y + v.z * w.z + v.w * w.w;
        #pragma unroll
        for (int off = 32; off > 0; off >>= 1)
            s += __shfl_down(s, off, 64);
        if (lane == 0) s_a[rr] = s;
    }

    // --- Lab dots: thread t computes m = t and m = t+256 (serial float4 dot).
    // lab is shared across all blocks -> L2/L3 broadcast after first touch.
    #pragma unroll
    for (int mm = 0; mm < 2; ++mm) {
        const int m = t + mm * 256;
        const float4* row = reinterpret_cast<const float4*>(lab + (size_t)m * FDIM);
        float acc = 0.0f;
        #pragma unroll 8
        for (int j = 0; j < FDIM / 4; ++j) {
            float4 v = row[j];
            float4 w = reinterpret_cast<const float4*>(s_w)[j];
            acc += v.x * w.x + v.y * w.y + v.z * w.z + v.w * w.w;
        }
        s_c[m] = acc;
    }

    __syncthreads();

    // --- Fill: 8 rows x 512 cols = 1024 float4 per block; 4 per thread.
    const float bb = bptr[0];
    float4* out4 = reinterpret_cast<float4*>(out + (size_t)blk * RPB * M_ROWS);
    #pragma unroll
    for (int k = 0; k < 4; ++k) {
        const int idx = k * 256 + t;       // 0..1023
        const int r   = idx >> 7;          // 0..7 (wave-uniform)
        const int mq  = idx & 127;         // float4 col index
        const float  a = s_a[r];
        const float4 c = reinterpret_cast<const float4*>(s_c)[mq];
        float4 o;
        o.x = a - c.x + bb;
        o.y = a - c.y + bb;
        o.z = a - c.z + bb;
        o.w = a - c.w + bb;
        out4[idx] = o;
    }
}

extern "C" void kernel_launch(void* const* d_in, const int* in_sizes, int n_in,
                              void* d_out, int out_size, void* d_ws, size_t ws_size,
                              hipStream_t stream) {
    const float* note = (const float*)d_in[0];   // [N, F]
    const float* lab  = (const float*)d_in[1];   // [M, F]
    const float* W    = (const float*)d_in[2];   // [F]
    const float* b    = (const float*)d_in[3];   // [1]
    float* out        = (float*)d_out;           // [N, M]

    siamese_fused<<<NBLK, 256, 0, stream>>>(note, lab, W, b, out);
}